// Round 12
// baseline (272.972 us; speedup 1.0000x reference)
//
#include <hip/hip_runtime.h>

#define N_NODES 50000
#define DIM 128
#define E_EDGES 800000
#define L_LAYERS 3
#define MTPAD 3128        // padded row-tiles (391 blocks * 4 waves * 2 tiles)
#define NBUCK 98          // ceil(50000/512)
#define BCAP 9216         // bucket capacity: mean 8192 + 11 sigma
#define BSHIFT 9          // 512 nodes per bucket

#define CVT_BLOCKS 6250   // N*D/4/256
#define TRANS_BLOCKS 768  // 2*L*D*2D/256
#define PREP_BLOCKS 5

typedef __attribute__((ext_vector_type(4))) float f32x4;
typedef __attribute__((ext_vector_type(2))) _Float16 f16x2;
typedef __attribute__((ext_vector_type(4))) _Float16 f16x4;
typedef __attribute__((ext_vector_type(8))) _Float16 f16x8;

// fp8 e4m3 (OCP on gfx950) helpers via HW cvt ops
__device__ inline unsigned int pack4_fp8(float a, float b, float c, float d) {
    int pk = __builtin_amdgcn_cvt_pk_fp8_f32(a, b, 0, false);
    pk = __builtin_amdgcn_cvt_pk_fp8_f32(c, d, pk, true);
    return (unsigned int)pk;
}

// ---- setup: x fp32->fp16 + fp8 shadow, W1/W2 -> fragment order, BN fold, gcur init ----
__global__ __launch_bounds__(256) void setup_kernel(
        const float4* __restrict__ x4, f16x4* __restrict__ h16o,
        unsigned int* __restrict__ h8o,
        const float* __restrict__ w1, const float* __restrict__ w2,
        _Float16* __restrict__ f1, _Float16* __restrict__ f2,
        const float* __restrict__ b1, const float* __restrict__ g1,
        const float* __restrict__ be1, const float* __restrict__ m1,
        const float* __restrict__ v1, const float* __restrict__ b2,
        const float* __restrict__ go, const float* __restrict__ bo,
        const float* __restrict__ mo, const float* __restrict__ vo,
        float* __restrict__ scale1, float* __restrict__ shift1,
        float* __restrict__ scale2, float* __restrict__ shift2,
        int* __restrict__ gcur) {
    const int b = blockIdx.x;
    const int t = threadIdx.x;
    if (b < CVT_BLOCKS) {
        int i = b * 256 + t;
        float4 v = x4[i];
        f16x4 o;
        o[0] = (_Float16)v.x; o[1] = (_Float16)v.y;
        o[2] = (_Float16)v.z; o[3] = (_Float16)v.w;
        h16o[i] = o;
        h8o[i] = pack4_fp8(v.x, v.y, v.z, v.w);
    } else if (b < CVT_BLOCKS + TRANS_BLOCKS) {
        int idx = (b - CVT_BLOCKS) * 256 + t;
        const int per = DIM * 2 * DIM;             // 32768
        const int tot = L_LAYERS * per;
        const float* w;
        _Float16* f;
        int K, Nn, id;
        if (idx < tot) { w = w1; f = f1; K = DIM; Nn = 2 * DIM; id = idx; }
        else           { w = w2; f = f2; K = 2 * DIM; Nn = DIM; id = idx - tot; }
        int l = id / per;
        int r = id - l * per;
        int k = r / Nn;
        int n = r - k * Nn;
        int KS = K >> 5;
        int off = ((((n >> 4) * KS + (k >> 5)) * 4 + ((k >> 3) & 3)) * 16 + (n & 15)) * 8 + (k & 7);
        f[(size_t)l * per + off] = (_Float16)w[id];
    } else if (b < CVT_BLOCKS + TRANS_BLOCKS + PREP_BLOCKS) {
        int idx = (b - (CVT_BLOCKS + TRANS_BLOCKS)) * 256 + t;
        if (idx < L_LAYERS * 256) {
            float sv = g1[idx] * rsqrtf(v1[idx] + 1e-5f);
            scale1[idx] = sv;
            shift1[idx] = (b1[idx] - m1[idx]) * sv + be1[idx];
        }
        int idx2 = idx - L_LAYERS * 256;
        if (idx2 >= 0 && idx2 < L_LAYERS * 128) {
            int l = idx2 >> 7;
            if (l < L_LAYERS - 1) {
                float sv = go[idx2] * rsqrtf(vo[idx2] + 1e-5f);
                scale2[idx2] = sv;
                shift2[idx2] = (b2[idx2] - mo[idx2]) * sv + bo[idx2];
            } else {
                scale2[idx2] = 1.0f;
                shift2[idx2] = b2[idx2];
            }
        }
    } else {
        if (t < NBUCK) gcur[t] = t * BCAP;
    }
}

// ================= binned CSR build =================

__global__ __launch_bounds__(256) void bin_kernel(const int* __restrict__ ei,
                                                  int* __restrict__ gcur,
                                                  unsigned int* __restrict__ brec) {
    __shared__ int cnt[NBUCK];
    __shared__ int off[NBUCK];
    __shared__ int gbase[NBUCK];
    __shared__ unsigned int rec[4096];
    const int t = threadIdx.x;
    const int start = blockIdx.x * 4096;
    for (int i = t; i < NBUCK; i += 256) cnt[i] = 0;
    __syncthreads();
    unsigned int myrec[16];
    unsigned int mypos[16];
    int nmine = 0;
    #pragma unroll
    for (int i = 0; i < 16; ++i) {
        int e = start + i * 256 + t;
        if (e < E_EDGES) {
            int src = ei[e];
            int dst = ei[E_EDGES + e];
            int b = dst >> BSHIFT;
            int idx = atomicAdd(&cnt[b], 1);
            myrec[i] = ((unsigned int)(dst & 511) << 16) | (unsigned int)src;
            mypos[i] = ((unsigned int)b << 16) | (unsigned int)idx;
            nmine = i + 1;
        }
    }
    __syncthreads();
    if (t == 0) {
        int s = 0;
        for (int b = 0; b < NBUCK; ++b) { off[b] = s; s += cnt[b]; }
    }
    __syncthreads();
    #pragma unroll
    for (int i = 0; i < 16; ++i) {
        if (i < nmine) {
            int b = mypos[i] >> 16;
            int idx = mypos[i] & 0xFFFF;
            rec[off[b] + idx] = myrec[i];
        }
    }
    __syncthreads();
    if (t < NBUCK && cnt[t] > 0) gbase[t] = atomicAdd(&gcur[t], cnt[t]);
    __syncthreads();
    const int wv = t >> 6, lane = t & 63;
    for (int b = wv; b < NBUCK; b += 4) {
        int c = cnt[b], o = off[b], g = gbase[b];
        for (int j = lane; j < c; j += 64)
            brec[g + j] = rec[o + j];
    }
}

// bsort v2: 512 threads/block; inlined bscan with wsum[8]. (verified r9/r10)
__global__ __launch_bounds__(512) void bsort_kernel(const unsigned int* __restrict__ brec,
                                                    const int* __restrict__ gcur,
                                                    int* __restrict__ rowp,
                                                    unsigned short* __restrict__ col) {
    __shared__ int ncnt[512];
    __shared__ int noff[512];
    __shared__ int wsum[8];
    __shared__ unsigned short srcbuf[BCAP];
    const int b = blockIdx.x;
    const int t = threadIdx.x;
    const int lane = t & 63;
    const int wv = t >> 6;                          // 0..7
    int pv = (t < b) ? (gcur[t] - t * BCAP) : 0;    // b <= 97 so only t<98 reads gcur
    #pragma unroll
    for (int d = 1; d < 64; d <<= 1) pv += __shfl_xor(pv, d, 64);
    if (lane == 0) wsum[wv] = pv;
    if (b == 0 && t == 0) rowp[N_NODES] = E_EDGES;
    const int cnt = gcur[b] - b * BCAP;
    const unsigned int* r = brec + (size_t)b * BCAP;
    ncnt[t] = 0;
    __syncthreads();
    int cb = 0;
    #pragma unroll
    for (int k = 0; k < 8; ++k) cb += wsum[k];
    for (int j = t; j < cnt; j += 512)
        atomicAdd(&ncnt[r[j] >> 16], 1);
    __syncthreads();          // all threads hold cb before wsum reuse below
    if (t < 256) {
        int a0 = ncnt[2 * t], a1 = ncnt[2 * t + 1];
        int pair = a0 + a1;
        int inc = pair;
        #pragma unroll
        for (int d = 1; d < 64; d <<= 1) {
            int u = __shfl_up(inc, d, 64);
            if (lane >= d) inc += u;
        }
        if (lane == 63) wsum[wv] = inc;
        __syncthreads();
        int wo = 0;
        if (wv > 0) wo = wsum[0];
        if (wv > 1) wo += wsum[1];
        if (wv > 2) wo += wsum[2];
        int excl = wo + inc - pair;
        noff[2 * t] = excl;
        noff[2 * t + 1] = excl + a0;
    } else {
        __syncthreads();
    }
    __syncthreads();
    const int n0 = b << BSHIFT;
    {
        int node = n0 + t;
        if (node < N_NODES) rowp[node] = cb + noff[t];
        ncnt[t] = noff[t];
    }
    __syncthreads();
    for (int j = t; j < cnt; j += 512) {
        unsigned int v = r[j];
        int pos = atomicAdd(&ncnt[v >> 16], 1);
        srcbuf[pos] = (unsigned short)(v & 0xFFFFu);
    }
    __syncthreads();
    unsigned short* cp = col + cb;
    for (int j = t; j < cnt; j += 512) cp[j] = srcbuf[j];
}

// ---- aggregation v6: pad-free fp8 paired gather.
// Main loop: UNMASKED floor(deg/16) paired batches (no clamp math, zero fake
// slots). Tail: ceil(rem/2)<=8 pair-loads under wave-uniform branches into
// pre-zeroed regs; loads are separated from consumption (issue all, then
// accumulate) so the tail costs ONE latency layer, not a serial chain; a
// per-lane validity mask is ANDed at accumulate time (fp8 0x00 == 0.0) so
// the odd-edge straddle contributes nothing. Removes the 35%-fake VMEM
// traffic (440k->~25k rows/layer) and the whole pad-correction path. ----
__global__ __launch_bounds__(256) void aggregate_kernel(
        const unsigned int* __restrict__ h16,
        const unsigned int* __restrict__ h8,     // fp8 rows: 32 dwords/row
        const int* __restrict__ row, const unsigned short* __restrict__ col,
        const float* __restrict__ epsp,
        unsigned short* __restrict__ zf) {
    const int wv = threadIdx.x >> 6;
    const int lane = threadIdx.x & 63;
    const int half = lane >> 5;
    const int m = lane & 31;
    const int node = blockIdx.x * 4 + wv;            // grid = 12500 exactly
    const f16x4* __restrict__ h4 = (const f16x4*)h16;  // 8B units, 32 per row
    const float s = 1.0f + epsp[0];
    f16x4 hv = h4[(size_t)node * 32 + m];
    float h0 = (float)hv[0], h1 = (float)hv[1], h2 = (float)hv[2], h3 = (float)hv[3];
    float a0 = 0.f, a1 = 0.f, a2 = 0.f, a3 = 0.f;
    const int e0 = row[node], e1 = row[node + 1];
    int e = e0;
    // ---- main: unmasked full 16-edge paired batches ----
    for (; e + 16 <= e1; e += 16) {
        int idx[8];
        #pragma unroll
        for (int p = 0; p < 8; ++p)
            idx[p] = (int)col[e + 2 * p + half];
        int w0 = (int)h8[(size_t)idx[0] * 32 + m];
        int w1 = (int)h8[(size_t)idx[1] * 32 + m];
        int w2 = (int)h8[(size_t)idx[2] * 32 + m];
        int w3 = (int)h8[(size_t)idx[3] * 32 + m];
        int w4 = (int)h8[(size_t)idx[4] * 32 + m];
        int w5 = (int)h8[(size_t)idx[5] * 32 + m];
        int w6 = (int)h8[(size_t)idx[6] * 32 + m];
        int w7 = (int)h8[(size_t)idx[7] * 32 + m];
        a0 += ((__builtin_amdgcn_cvt_f32_fp8(w0, 0) + __builtin_amdgcn_cvt_f32_fp8(w1, 0))
             + (__builtin_amdgcn_cvt_f32_fp8(w2, 0) + __builtin_amdgcn_cvt_f32_fp8(w3, 0)))
            + ((__builtin_amdgcn_cvt_f32_fp8(w4, 0) + __builtin_amdgcn_cvt_f32_fp8(w5, 0))
             + (__builtin_amdgcn_cvt_f32_fp8(w6, 0) + __builtin_amdgcn_cvt_f32_fp8(w7, 0)));
        a1 += ((__builtin_amdgcn_cvt_f32_fp8(w0, 1) + __builtin_amdgcn_cvt_f32_fp8(w1, 1))
             + (__builtin_amdgcn_cvt_f32_fp8(w2, 1) + __builtin_amdgcn_cvt_f32_fp8(w3, 1)))
            + ((__builtin_amdgcn_cvt_f32_fp8(w4, 1) + __builtin_amdgcn_cvt_f32_fp8(w5, 1))
             + (__builtin_amdgcn_cvt_f32_fp8(w6, 1) + __builtin_amdgcn_cvt_f32_fp8(w7, 1)));
        a2 += ((__builtin_amdgcn_cvt_f32_fp8(w0, 2) + __builtin_amdgcn_cvt_f32_fp8(w1, 2))
             + (__builtin_amdgcn_cvt_f32_fp8(w2, 2) + __builtin_amdgcn_cvt_f32_fp8(w3, 2)))
            + ((__builtin_amdgcn_cvt_f32_fp8(w4, 2) + __builtin_amdgcn_cvt_f32_fp8(w5, 2))
             + (__builtin_amdgcn_cvt_f32_fp8(w6, 2) + __builtin_amdgcn_cvt_f32_fp8(w7, 2)));
        a3 += ((__builtin_amdgcn_cvt_f32_fp8(w0, 3) + __builtin_amdgcn_cvt_f32_fp8(w1, 3))
             + (__builtin_amdgcn_cvt_f32_fp8(w2, 3) + __builtin_amdgcn_cvt_f32_fp8(w3, 3)))
            + ((__builtin_amdgcn_cvt_f32_fp8(w4, 3) + __builtin_amdgcn_cvt_f32_fp8(w5, 3))
             + (__builtin_amdgcn_cvt_f32_fp8(w6, 3) + __builtin_amdgcn_cvt_f32_fp8(w7, 3)));
    }
    // ---- tail: rem in [0,16); issue ceil(rem/2) pair-loads, accumulate after ----
    const int rem = e1 - e;
    if (rem > 0) {
        const int np = (rem + 1) >> 1;
        unsigned int wreg[8] = {0u, 0u, 0u, 0u, 0u, 0u, 0u, 0u};
        unsigned int vmsk[8] = {0u, 0u, 0u, 0u, 0u, 0u, 0u, 0u};
        #pragma unroll
        for (int p = 0; p < 8; ++p) {
            if (p < np) {                       // wave-uniform branch
                int ee = e + 2 * p + half;
                int valid = (ee < e1) ? 1 : 0;
                int cc = (int)col[valid ? ee : (e1 - 1)];
                wreg[p] = h8[(size_t)(valid ? cc : node) * 32 + m];
                vmsk[p] = valid ? ~0u : 0u;
            }
        }
        #pragma unroll
        for (int p = 0; p < 8; ++p) {
            int w = (int)(wreg[p] & vmsk[p]);   // fp8 0x00 decodes to 0.0
            a0 += __builtin_amdgcn_cvt_f32_fp8(w, 0);
            a1 += __builtin_amdgcn_cvt_f32_fp8(w, 1);
            a2 += __builtin_amdgcn_cvt_f32_fp8(w, 2);
            a3 += __builtin_amdgcn_cvt_f32_fp8(w, 3);
        }
    }
    a0 += __shfl_xor(a0, 32, 64);
    a1 += __shfl_xor(a1, 32, 64);
    a2 += __shfl_xor(a2, 32, 64);
    a3 += __shfl_xor(a3, 32, 64);
    float t0 = s * h0 + a0;
    float t1 = s * h1 + a1;
    float t2 = s * h2 + a2;
    float t3 = s * h3 + a3;
    if (half == 0) {
        unsigned int lo = (unsigned int)__builtin_bit_cast(unsigned short, (_Float16)t0)
                        | ((unsigned int)__builtin_bit_cast(unsigned short, (_Float16)t1) << 16);
        unsigned int hi = (unsigned int)__builtin_bit_cast(unsigned short, (_Float16)t2)
                        | ((unsigned int)__builtin_bit_cast(unsigned short, (_Float16)t3) << 16);
        int mt = node >> 4, r16 = node & 15;
        int ks = m >> 3, quad = (m >> 1) & 3, j0 = (m & 1) * 4;
        size_t zo = (((size_t)(mt * 4 + ks)) * 4 + quad) * 128 + r16 * 8 + j0;
        uint2 pk; pk.x = lo; pk.y = hi;
        *(uint2*)(zf + zo) = pk;
    }
}

// ---- MLP v2: each wave owns TWO 16-row tiles (32 rows); every B-fragment
// ds_read feeds 2 MFMAs. grid = 391 (MTPAD/8). LDS = 64KB -> 2 blk/CU.
// Epilogue writes the fp8 shadow of h for the next layer's gather. ----
__global__ __launch_bounds__(256) void mlp_kernel(
        const _Float16* __restrict__ zf,
        const _Float16* __restrict__ w1f, const _Float16* __restrict__ w2f,
        const float* __restrict__ scale1, const float* __restrict__ shift1,
        const float* __restrict__ scale2, const float* __restrict__ shift2,
        int last,
        unsigned short* __restrict__ h16out, unsigned char* __restrict__ h8out,
        float* __restrict__ lsout) {
    __shared__ _Float16 wbuf[16384];        // 32KB staged weight chunk (w1 then w2)
    __shared__ _Float16 tbuf[4][2][2048];   // per-wave, per-tile hidden (16 planes*128)
    const int tid = threadIdx.x;
    const int wave = tid >> 6;
    const int lane = tid & 63;
    const int quad = lane >> 4;
    const int l16 = lane & 15;
    const int mt0 = blockIdx.x * 8 + wave * 2;   // tiles mt0, mt0+1 (< MTPAD)

    // A fragments: 2 tiles x (16 rows x K=128)
    f16x8 ah[2][4];
    #pragma unroll
    for (int tt = 0; tt < 2; ++tt)
        #pragma unroll
        for (int ks = 0; ks < 4; ++ks)
            ah[tt][ks] = *(const f16x8*)(zf + (((size_t)((mt0 + tt) * 4 + ks)) << 9) + lane * 8);

    f32x4 acc2[2][8] = {};
    #pragma unroll
    for (int c = 0; c < 2; ++c) {
        // ---- stage w1 chunk c: 16384 halfwords contiguous ----
        {
            const _Float16* g = w1f + c * 16384 + tid * 8;
            _Float16* l = wbuf + tid * 8;
            #pragma unroll
            for (int j = 0; j < 8; ++j)
                *(f16x8*)(l + j * 2048) = *(const f16x8*)(g + j * 2048);
        }
        __syncthreads();
        // ---- phase 1: hidden cols [128c,128c+128), B from LDS, 2 tiles/B-read ----
        #pragma unroll
        for (int ntl = 0; ntl < 8; ++ntl) {
            f32x4 acc[2] = {};
            #pragma unroll
            for (int ks = 0; ks < 4; ++ks) {
                f16x8 bfr = *(const f16x8*)&wbuf[(ntl * 4 + ks) * 512 + lane * 8];
                acc[0] = __builtin_amdgcn_mfma_f32_16x16x32_f16(ah[0][ks], bfr, acc[0], 0, 0, 0);
                acc[1] = __builtin_amdgcn_mfma_f32_16x16x32_f16(ah[1][ks], bfr, acc[1], 0, 0, 0);
            }
            int cg = (c * 8 + ntl) * 16 + l16;
            float sc = scale1[cg];
            float sh = shift1[cg];
            int plane = (cg >> 3) & 15;
            int basei = plane * 128 + (cg & 7);
            #pragma unroll
            for (int tt = 0; tt < 2; ++tt)
                #pragma unroll
                for (int r = 0; r < 4; ++r) {
                    float val = fmaxf(acc[tt][r] * sc + sh, 0.0f);
                    tbuf[wave][tt][basei + (quad * 4 + r) * 8] = (_Float16)val;
                }
        }
        __syncthreads();
        // ---- stage w2 chunk c: 8 pieces of 2048 halfwords ----
        {
            #pragma unroll
            for (int nt = 0; nt < 8; ++nt) {
                *(f16x8*)&wbuf[nt * 2048 + tid * 8] =
                    *(const f16x8*)(w2f + (((size_t)(nt * 8 + c * 4)) << 9) + tid * 8);
            }
        }
        __syncthreads();
        // ---- phase 2: k in [128c,128c+128), B from LDS, 2 tiles/B-read ----
        #pragma unroll
        for (int ks4 = 0; ks4 < 4; ++ks4) {
            int po = (ks4 * 4 + quad) * 128 + l16 * 8;
            f16x8 a2_0 = *(const f16x8*)&tbuf[wave][0][po];
            f16x8 a2_1 = *(const f16x8*)&tbuf[wave][1][po];
            #pragma unroll
            for (int nt = 0; nt < 8; ++nt) {
                f16x8 bfr = *(const f16x8*)&wbuf[(nt * 4 + ks4) * 512 + lane * 8];
                acc2[0][nt] = __builtin_amdgcn_mfma_f32_16x16x32_f16(a2_0, bfr, acc2[0][nt], 0, 0, 0);
                acc2[1][nt] = __builtin_amdgcn_mfma_f32_16x16x32_f16(a2_1, bfr, acc2[1][nt], 0, 0, 0);
            }
        }
        __syncthreads();
    }

    #pragma unroll
    for (int nt = 0; nt < 8; ++nt) {
        int cg = nt * 16 + l16;
        float sc = scale2[cg];
        float sh = shift2[cg];
        #pragma unroll
        for (int tt = 0; tt < 2; ++tt)
            #pragma unroll
            for (int r = 0; r < 4; ++r)
                acc2[tt][nt][r] = acc2[tt][nt][r] * sc + sh;
    }
    if (!last) {
        #pragma unroll
        for (int tt = 0; tt < 2; ++tt) {
            const int R0 = (mt0 + tt) * 16;
            #pragma unroll
            for (int nt = 0; nt < 8; ++nt) {
                int cg = nt * 16 + l16;
                #pragma unroll
                for (int r = 0; r < 4; ++r) {
                    int rg = R0 + quad * 4 + r;
                    if (rg < N_NODES) {
                        float val = fmaxf(acc2[tt][nt][r], 0.0f);
                        h16out[(size_t)rg * DIM + cg] =
                            __builtin_bit_cast(unsigned short, (_Float16)val);
                        unsigned int pk = (unsigned int)
                            __builtin_amdgcn_cvt_pk_fp8_f32(val, 0.0f, 0, false);
                        h8out[(size_t)rg * DIM + cg] = (unsigned char)(pk & 0xFF);
                    }
                }
            }
        }
    } else {
        #pragma unroll
        for (int tt = 0; tt < 2; ++tt) {
            const int R0 = (mt0 + tt) * 16;
            #pragma unroll
            for (int r = 0; r < 4; ++r) {
                float mx = acc2[tt][0][r];
                #pragma unroll
                for (int nt = 1; nt < 8; ++nt) mx = fmaxf(mx, acc2[tt][nt][r]);
                #pragma unroll
                for (int off = 1; off < 16; off <<= 1) mx = fmaxf(mx, __shfl_xor(mx, off, 64));
                float sum = 0.0f;
                #pragma unroll
                for (int nt = 0; nt < 8; ++nt) sum += expf(acc2[tt][nt][r] - mx);
                #pragma unroll
                for (int off = 1; off < 16; off <<= 1) sum += __shfl_xor(sum, off, 64);
                float ls = mx + logf(sum);
                int rg = R0 + quad * 4 + r;
                if (rg < N_NODES) {
                    #pragma unroll
                    for (int nt = 0; nt < 8; ++nt)
                        lsout[(size_t)rg * DIM + nt * 16 + l16] = acc2[tt][nt][r] - ls;
                }
            }
        }
    }
}

extern "C" void kernel_launch(void* const* d_in, const int* in_sizes, int n_in,
                              void* d_out, int out_size, void* d_ws, size_t ws_size,
                              hipStream_t stream) {
    const float* x   = (const float*)d_in[0];
    const int*   ei  = (const int*)d_in[1];
    const float* W1  = (const float*)d_in[2];
    const float* b1  = (const float*)d_in[3];
    const float* g1  = (const float*)d_in[4];
    const float* be1 = (const float*)d_in[5];
    const float* m1  = (const float*)d_in[6];
    const float* v1  = (const float*)d_in[7];
    const float* W2  = (const float*)d_in[8];
    const float* b2  = (const float*)d_in[9];
    const float* eps = (const float*)d_in[10];
    const float* go  = (const float*)d_in[11];
    const float* bo  = (const float*)d_in[12];
    const float* mo  = (const float*)d_in[13];
    const float* vo  = (const float*)d_in[14];

    char* ws = (char*)d_ws;
    unsigned short* h16 = (unsigned short*)ws;  ws += (size_t)N_NODES * DIM * 2;
    unsigned char* h8 = (unsigned char*)ws;     ws += (size_t)N_NODES * DIM;
    unsigned short* zf = (unsigned short*)ws;   ws += (size_t)MTPAD * 2048 * 2;
    _Float16* w1f = (_Float16*)ws;              ws += (size_t)L_LAYERS * 32768 * 2;
    _Float16* w2f = (_Float16*)ws;              ws += (size_t)L_LAYERS * 32768 * 2;
    float* scale1 = (float*)ws; ws += (size_t)L_LAYERS * 256 * 4;
    float* shift1 = (float*)ws; ws += (size_t)L_LAYERS * 256 * 4;
    float* scale2 = (float*)ws; ws += (size_t)L_LAYERS * 128 * 4;
    float* shift2 = (float*)ws; ws += (size_t)L_LAYERS * 128 * 4;
    unsigned int* brec = (unsigned int*)ws; ws += (size_t)NBUCK * BCAP * 4;
    int* gcur = (int*)ws; ws += 128 * 4;
    int* rowp = (int*)ws; ws += (size_t)(N_NODES + 1) * 4;
    unsigned short* col = (unsigned short*)ws; ws += (size_t)E_EDGES * 2;

    setup_kernel<<<CVT_BLOCKS + TRANS_BLOCKS + PREP_BLOCKS + 1, 256, 0, stream>>>(
        (const float4*)x, (f16x4*)h16, (unsigned int*)h8, W1, W2, w1f, w2f,
        b1, g1, be1, m1, v1, b2, go, bo, mo, vo,
        scale1, shift1, scale2, shift2, gcur);
    bin_kernel<<<(E_EDGES + 4095) / 4096, 256, 0, stream>>>(ei, gcur, brec);
    bsort_kernel<<<NBUCK, 512, 0, stream>>>(brec, gcur, rowp, col);

    for (int i = 0; i < L_LAYERS; ++i) {
        aggregate_kernel<<<N_NODES / 4, 256, 0, stream>>>((const unsigned int*)h16,
                                                          (const unsigned int*)h8,
                                                          rowp, col, eps + i, zf);
        int last = (i == L_LAYERS - 1) ? 1 : 0;
        mlp_kernel<<<MTPAD / 8, 256, 0, stream>>>((const _Float16*)zf,
            w1f + (size_t)i * 32768, w2f + (size_t)i * 32768,
            scale1 + i * 256, shift1 + i * 256,
            scale2 + i * 128, shift2 + i * 128,
            last, h16, h8, (float*)d_out);
    }
}

// Round 13
// 265.037 us; speedup vs baseline: 1.0299x; 1.0299x over previous
//
#include <hip/hip_runtime.h>

#define N_NODES 50000
#define DIM 128
#define E_EDGES 800000
#define L_LAYERS 3
#define MTPAD 3128        // padded row-tiles (391 blocks * 4 waves * 2 tiles)
#define NBUCK 98          // ceil(50000/512)
#define BCAP 9216         // bucket capacity: mean 8192 + 11 sigma
#define BSHIFT 9          // 512 nodes per bucket

#define CVT_BLOCKS 6250   // N*D/4/256
#define TRANS_BLOCKS 768  // 2*L*D*2D/256
#define PREP_BLOCKS 5

typedef __attribute__((ext_vector_type(4))) float f32x4;
typedef __attribute__((ext_vector_type(2))) _Float16 f16x2;
typedef __attribute__((ext_vector_type(4))) _Float16 f16x4;
typedef __attribute__((ext_vector_type(8))) _Float16 f16x8;

// fp8 e4m3 (OCP on gfx950) helpers via HW cvt ops
__device__ inline unsigned int pack4_fp8(float a, float b, float c, float d) {
    int pk = __builtin_amdgcn_cvt_pk_fp8_f32(a, b, 0, false);
    pk = __builtin_amdgcn_cvt_pk_fp8_f32(c, d, pk, true);
    return (unsigned int)pk;
}

// ---- setup: x fp32->fp16 + fp8 shadow, W1/W2 -> fragment order, BN fold, gcur init ----
__global__ __launch_bounds__(256) void setup_kernel(
        const float4* __restrict__ x4, f16x4* __restrict__ h16o,
        unsigned int* __restrict__ h8o,
        const float* __restrict__ w1, const float* __restrict__ w2,
        _Float16* __restrict__ f1, _Float16* __restrict__ f2,
        const float* __restrict__ b1, const float* __restrict__ g1,
        const float* __restrict__ be1, const float* __restrict__ m1,
        const float* __restrict__ v1, const float* __restrict__ b2,
        const float* __restrict__ go, const float* __restrict__ bo,
        const float* __restrict__ mo, const float* __restrict__ vo,
        float* __restrict__ scale1, float* __restrict__ shift1,
        float* __restrict__ scale2, float* __restrict__ shift2,
        int* __restrict__ gcur) {
    const int b = blockIdx.x;
    const int t = threadIdx.x;
    if (b < CVT_BLOCKS) {
        int i = b * 256 + t;
        float4 v = x4[i];
        f16x4 o;
        o[0] = (_Float16)v.x; o[1] = (_Float16)v.y;
        o[2] = (_Float16)v.z; o[3] = (_Float16)v.w;
        h16o[i] = o;
        h8o[i] = pack4_fp8(v.x, v.y, v.z, v.w);
    } else if (b < CVT_BLOCKS + TRANS_BLOCKS) {
        int idx = (b - CVT_BLOCKS) * 256 + t;
        const int per = DIM * 2 * DIM;             // 32768
        const int tot = L_LAYERS * per;
        const float* w;
        _Float16* f;
        int K, Nn, id;
        if (idx < tot) { w = w1; f = f1; K = DIM; Nn = 2 * DIM; id = idx; }
        else           { w = w2; f = f2; K = 2 * DIM; Nn = DIM; id = idx - tot; }
        int l = id / per;
        int r = id - l * per;
        int k = r / Nn;
        int n = r - k * Nn;
        int KS = K >> 5;
        int off = ((((n >> 4) * KS + (k >> 5)) * 4 + ((k >> 3) & 3)) * 16 + (n & 15)) * 8 + (k & 7);
        f[(size_t)l * per + off] = (_Float16)w[id];
    } else if (b < CVT_BLOCKS + TRANS_BLOCKS + PREP_BLOCKS) {
        int idx = (b - (CVT_BLOCKS + TRANS_BLOCKS)) * 256 + t;
        if (idx < L_LAYERS * 256) {
            float sv = g1[idx] * rsqrtf(v1[idx] + 1e-5f);
            scale1[idx] = sv;
            shift1[idx] = (b1[idx] - m1[idx]) * sv + be1[idx];
        }
        int idx2 = idx - L_LAYERS * 256;
        if (idx2 >= 0 && idx2 < L_LAYERS * 128) {
            int l = idx2 >> 7;
            if (l < L_LAYERS - 1) {
                float sv = go[idx2] * rsqrtf(vo[idx2] + 1e-5f);
                scale2[idx2] = sv;
                shift2[idx2] = (b2[idx2] - mo[idx2]) * sv + bo[idx2];
            } else {
                scale2[idx2] = 1.0f;
                shift2[idx2] = b2[idx2];
            }
        }
    } else {
        if (t < NBUCK) gcur[t] = t * BCAP;
    }
}

// ================= binned CSR build =================

__global__ __launch_bounds__(256) void bin_kernel(const int* __restrict__ ei,
                                                  int* __restrict__ gcur,
                                                  unsigned int* __restrict__ brec) {
    __shared__ int cnt[NBUCK];
    __shared__ int off[NBUCK];
    __shared__ int gbase[NBUCK];
    __shared__ unsigned int rec[4096];
    const int t = threadIdx.x;
    const int start = blockIdx.x * 4096;
    for (int i = t; i < NBUCK; i += 256) cnt[i] = 0;
    __syncthreads();
    unsigned int myrec[16];
    unsigned int mypos[16];
    int nmine = 0;
    #pragma unroll
    for (int i = 0; i < 16; ++i) {
        int e = start + i * 256 + t;
        if (e < E_EDGES) {
            int src = ei[e];
            int dst = ei[E_EDGES + e];
            int b = dst >> BSHIFT;
            int idx = atomicAdd(&cnt[b], 1);
            myrec[i] = ((unsigned int)(dst & 511) << 16) | (unsigned int)src;
            mypos[i] = ((unsigned int)b << 16) | (unsigned int)idx;
            nmine = i + 1;
        }
    }
    __syncthreads();
    if (t == 0) {
        int s = 0;
        for (int b = 0; b < NBUCK; ++b) { off[b] = s; s += cnt[b]; }
    }
    __syncthreads();
    #pragma unroll
    for (int i = 0; i < 16; ++i) {
        if (i < nmine) {
            int b = mypos[i] >> 16;
            int idx = mypos[i] & 0xFFFF;
            rec[off[b] + idx] = myrec[i];
        }
    }
    __syncthreads();
    if (t < NBUCK && cnt[t] > 0) gbase[t] = atomicAdd(&gcur[t], cnt[t]);
    __syncthreads();
    const int wv = t >> 6, lane = t & 63;
    for (int b = wv; b < NBUCK; b += 4) {
        int c = cnt[b], o = off[b], g = gbase[b];
        for (int j = lane; j < c; j += 64)
            brec[g + j] = rec[o + j];
    }
}

// bsort v2: 512 threads/block (98 blocks use <40% of CUs; per-block serial
// work halves). Scan phase stays on first 4 waves; inlined bscan uses wsum[8].
__global__ __launch_bounds__(512) void bsort_kernel(const unsigned int* __restrict__ brec,
                                                    const int* __restrict__ gcur,
                                                    int* __restrict__ rowp,
                                                    unsigned short* __restrict__ col) {
    __shared__ int ncnt[512];
    __shared__ int noff[512];
    __shared__ int wsum[8];
    __shared__ unsigned short srcbuf[BCAP];
    const int b = blockIdx.x;
    const int t = threadIdx.x;
    const int lane = t & 63;
    const int wv = t >> 6;                          // 0..7
    int pv = (t < b) ? (gcur[t] - t * BCAP) : 0;    // b <= 97 so only t<98 reads gcur
    #pragma unroll
    for (int d = 1; d < 64; d <<= 1) pv += __shfl_xor(pv, d, 64);
    if (lane == 0) wsum[wv] = pv;
    if (b == 0 && t == 0) rowp[N_NODES] = E_EDGES;
    const int cnt = gcur[b] - b * BCAP;
    const unsigned int* r = brec + (size_t)b * BCAP;
    ncnt[t] = 0;
    __syncthreads();
    int cb = 0;
    #pragma unroll
    for (int k = 0; k < 8; ++k) cb += wsum[k];
    for (int j = t; j < cnt; j += 512)
        atomicAdd(&ncnt[r[j] >> 16], 1);
    __syncthreads();          // all threads hold cb before wsum reuse below
    if (t < 256) {
        int a0 = ncnt[2 * t], a1 = ncnt[2 * t + 1];
        int pair = a0 + a1;
        int inc = pair;
        #pragma unroll
        for (int d = 1; d < 64; d <<= 1) {
            int u = __shfl_up(inc, d, 64);
            if (lane >= d) inc += u;
        }
        if (lane == 63) wsum[wv] = inc;
        __syncthreads();
        int wo = 0;
        if (wv > 0) wo = wsum[0];
        if (wv > 1) wo += wsum[1];
        if (wv > 2) wo += wsum[2];
        int excl = wo + inc - pair;
        noff[2 * t] = excl;
        noff[2 * t + 1] = excl + a0;
    } else {
        __syncthreads();
    }
    __syncthreads();
    const int n0 = b << BSHIFT;
    {
        int node = n0 + t;
        if (node < N_NODES) rowp[node] = cb + noff[t];
        ncnt[t] = noff[t];
    }
    __syncthreads();
    for (int j = t; j < cnt; j += 512) {
        unsigned int v = r[j];
        int pos = atomicAdd(&ncnt[v >> 16], 1);
        srcbuf[pos] = (unsigned short)(v & 0xFFFFu);
    }
    __syncthreads();
    unsigned short* cp = col + cb;
    for (int j = t; j < cnt; j += 512) cp[j] = srcbuf[j];
}

// ---- aggregation v5 (best measured): fp8 paired gather. Neighbor rows from
// the 128B/row fp8-e4m3 shadow; one dword-per-lane instruction over 32 lanes
// fetches TWO rows. Lane covers channels 4m..4m+3 (m=lane&31), decoded with
// HW v_cvt_f32_fp8. Self term stays fp16; fake slots clamp to the node's own
// fp8 row; over-count removed with DECODED fp8 self values (exact cancel).
// Local optimum proven by r6/r9/r12: wider windows, split passes, and
// branchy pad-elimination all regress; this uniform masked loop stands. ----
__global__ __launch_bounds__(256) void aggregate_kernel(
        const unsigned int* __restrict__ h16,
        const unsigned int* __restrict__ h8,     // fp8 rows: 32 dwords/row
        const int* __restrict__ row, const unsigned short* __restrict__ col,
        const float* __restrict__ epsp,
        unsigned short* __restrict__ zf) {
    const int wv = threadIdx.x >> 6;
    const int lane = threadIdx.x & 63;
    const int half = lane >> 5;
    const int m = lane & 31;
    const int node = blockIdx.x * 4 + wv;            // grid = 12500 exactly
    const f16x4* __restrict__ h4 = (const f16x4*)h16;  // 8B units, 32 per row
    const float s = 1.0f + epsp[0];
    f16x4 hv = h4[(size_t)node * 32 + m];
    float h0 = (float)hv[0], h1 = (float)hv[1], h2 = (float)hv[2], h3 = (float)hv[3];
    const int self8 = (int)h8[(size_t)node * 32 + m];
    float n0 = __builtin_amdgcn_cvt_f32_fp8(self8, 0);
    float n1 = __builtin_amdgcn_cvt_f32_fp8(self8, 1);
    float n2 = __builtin_amdgcn_cvt_f32_fp8(self8, 2);
    float n3 = __builtin_amdgcn_cvt_f32_fp8(self8, 3);
    float a0 = 0.f, a1 = 0.f, a2 = 0.f, a3 = 0.f;
    const int e0 = row[node], e1 = row[node + 1];
    int pad = 0;
    for (int e = e0; e < e1; e += 16) {
        int idx[8];
        #pragma unroll
        for (int p = 0; p < 8; ++p) {
            int ee = e + 2 * p + half;
            int cl = ee < E_EDGES - 1 ? ee : E_EDGES - 1;   // stay in col[]
            int cc = col[cl];
            idx[p] = (ee < e1) ? cc : node;
        }
        pad += (e + 16 > e1) ? (e + 16 - e1) : 0;
        int w0 = (int)h8[(size_t)idx[0] * 32 + m];
        int w1 = (int)h8[(size_t)idx[1] * 32 + m];
        int w2 = (int)h8[(size_t)idx[2] * 32 + m];
        int w3 = (int)h8[(size_t)idx[3] * 32 + m];
        int w4 = (int)h8[(size_t)idx[4] * 32 + m];
        int w5 = (int)h8[(size_t)idx[5] * 32 + m];
        int w6 = (int)h8[(size_t)idx[6] * 32 + m];
        int w7 = (int)h8[(size_t)idx[7] * 32 + m];
        a0 += ((__builtin_amdgcn_cvt_f32_fp8(w0, 0) + __builtin_amdgcn_cvt_f32_fp8(w1, 0))
             + (__builtin_amdgcn_cvt_f32_fp8(w2, 0) + __builtin_amdgcn_cvt_f32_fp8(w3, 0)))
            + ((__builtin_amdgcn_cvt_f32_fp8(w4, 0) + __builtin_amdgcn_cvt_f32_fp8(w5, 0))
             + (__builtin_amdgcn_cvt_f32_fp8(w6, 0) + __builtin_amdgcn_cvt_f32_fp8(w7, 0)));
        a1 += ((__builtin_amdgcn_cvt_f32_fp8(w0, 1) + __builtin_amdgcn_cvt_f32_fp8(w1, 1))
             + (__builtin_amdgcn_cvt_f32_fp8(w2, 1) + __builtin_amdgcn_cvt_f32_fp8(w3, 1)))
            + ((__builtin_amdgcn_cvt_f32_fp8(w4, 1) + __builtin_amdgcn_cvt_f32_fp8(w5, 1))
             + (__builtin_amdgcn_cvt_f32_fp8(w6, 1) + __builtin_amdgcn_cvt_f32_fp8(w7, 1)));
        a2 += ((__builtin_amdgcn_cvt_f32_fp8(w0, 2) + __builtin_amdgcn_cvt_f32_fp8(w1, 2))
             + (__builtin_amdgcn_cvt_f32_fp8(w2, 2) + __builtin_amdgcn_cvt_f32_fp8(w3, 2)))
            + ((__builtin_amdgcn_cvt_f32_fp8(w4, 2) + __builtin_amdgcn_cvt_f32_fp8(w5, 2))
             + (__builtin_amdgcn_cvt_f32_fp8(w6, 2) + __builtin_amdgcn_cvt_f32_fp8(w7, 2)));
        a3 += ((__builtin_amdgcn_cvt_f32_fp8(w0, 3) + __builtin_amdgcn_cvt_f32_fp8(w1, 3))
             + (__builtin_amdgcn_cvt_f32_fp8(w2, 3) + __builtin_amdgcn_cvt_f32_fp8(w3, 3)))
            + ((__builtin_amdgcn_cvt_f32_fp8(w4, 3) + __builtin_amdgcn_cvt_f32_fp8(w5, 3))
             + (__builtin_amdgcn_cvt_f32_fp8(w6, 3) + __builtin_amdgcn_cvt_f32_fp8(w7, 3)));
    }
    a0 += __shfl_xor(a0, 32, 64);
    a1 += __shfl_xor(a1, 32, 64);
    a2 += __shfl_xor(a2, 32, 64);
    a3 += __shfl_xor(a3, 32, 64);
    const float fpad = (float)pad;
    float t0 = s * h0 + a0 - fpad * n0;
    float t1 = s * h1 + a1 - fpad * n1;
    float t2 = s * h2 + a2 - fpad * n2;
    float t3 = s * h3 + a3 - fpad * n3;
    if (half == 0) {
        unsigned int lo = (unsigned int)__builtin_bit_cast(unsigned short, (_Float16)t0)
                        | ((unsigned int)__builtin_bit_cast(unsigned short, (_Float16)t1) << 16);
        unsigned int hi = (unsigned int)__builtin_bit_cast(unsigned short, (_Float16)t2)
                        | ((unsigned int)__builtin_bit_cast(unsigned short, (_Float16)t3) << 16);
        int mt = node >> 4, r16 = node & 15;
        int ks = m >> 3, quad = (m >> 1) & 3, j0 = (m & 1) * 4;
        size_t zo = (((size_t)(mt * 4 + ks)) * 4 + quad) * 128 + r16 * 8 + j0;
        uint2 pk; pk.x = lo; pk.y = hi;
        *(uint2*)(zf + zo) = pk;
    }
}

// ---- MLP v2: each wave owns TWO 16-row tiles (32 rows); every B-fragment
// ds_read feeds 2 MFMAs. grid = 391 (MTPAD/8). LDS = 64KB -> 2 blk/CU.
// Epilogue writes the fp8 shadow of h for the next layer's gather. ----
__global__ __launch_bounds__(256) void mlp_kernel(
        const _Float16* __restrict__ zf,
        const _Float16* __restrict__ w1f, const _Float16* __restrict__ w2f,
        const float* __restrict__ scale1, const float* __restrict__ shift1,
        const float* __restrict__ scale2, const float* __restrict__ shift2,
        int last,
        unsigned short* __restrict__ h16out, unsigned char* __restrict__ h8out,
        float* __restrict__ lsout) {
    __shared__ _Float16 wbuf[16384];        // 32KB staged weight chunk (w1 then w2)
    __shared__ _Float16 tbuf[4][2][2048];   // per-wave, per-tile hidden (16 planes*128)
    const int tid = threadIdx.x;
    const int wave = tid >> 6;
    const int lane = tid & 63;
    const int quad = lane >> 4;
    const int l16 = lane & 15;
    const int mt0 = blockIdx.x * 8 + wave * 2;   // tiles mt0, mt0+1 (< MTPAD)

    // A fragments: 2 tiles x (16 rows x K=128)
    f16x8 ah[2][4];
    #pragma unroll
    for (int tt = 0; tt < 2; ++tt)
        #pragma unroll
        for (int ks = 0; ks < 4; ++ks)
            ah[tt][ks] = *(const f16x8*)(zf + (((size_t)((mt0 + tt) * 4 + ks)) << 9) + lane * 8);

    f32x4 acc2[2][8] = {};
    #pragma unroll
    for (int c = 0; c < 2; ++c) {
        // ---- stage w1 chunk c: 16384 halfwords contiguous ----
        {
            const _Float16* g = w1f + c * 16384 + tid * 8;
            _Float16* l = wbuf + tid * 8;
            #pragma unroll
            for (int j = 0; j < 8; ++j)
                *(f16x8*)(l + j * 2048) = *(const f16x8*)(g + j * 2048);
        }
        __syncthreads();
        // ---- phase 1: hidden cols [128c,128c+128), B from LDS, 2 tiles/B-read ----
        #pragma unroll
        for (int ntl = 0; ntl < 8; ++ntl) {
            f32x4 acc[2] = {};
            #pragma unroll
            for (int ks = 0; ks < 4; ++ks) {
                f16x8 bfr = *(const f16x8*)&wbuf[(ntl * 4 + ks) * 512 + lane * 8];
                acc[0] = __builtin_amdgcn_mfma_f32_16x16x32_f16(ah[0][ks], bfr, acc[0], 0, 0, 0);
                acc[1] = __builtin_amdgcn_mfma_f32_16x16x32_f16(ah[1][ks], bfr, acc[1], 0, 0, 0);
            }
            int cg = (c * 8 + ntl) * 16 + l16;
            float sc = scale1[cg];
            float sh = shift1[cg];
            int plane = (cg >> 3) & 15;
            int basei = plane * 128 + (cg & 7);
            #pragma unroll
            for (int tt = 0; tt < 2; ++tt)
                #pragma unroll
                for (int r = 0; r < 4; ++r) {
                    float val = fmaxf(acc[tt][r] * sc + sh, 0.0f);
                    tbuf[wave][tt][basei + (quad * 4 + r) * 8] = (_Float16)val;
                }
        }
        __syncthreads();
        // ---- stage w2 chunk c: 8 pieces of 2048 halfwords ----
        {
            #pragma unroll
            for (int nt = 0; nt < 8; ++nt) {
                *(f16x8*)&wbuf[nt * 2048 + tid * 8] =
                    *(const f16x8*)(w2f + (((size_t)(nt * 8 + c * 4)) << 9) + tid * 8);
            }
        }
        __syncthreads();
        // ---- phase 2: k in [128c,128c+128), B from LDS, 2 tiles/B-read ----
        #pragma unroll
        for (int ks4 = 0; ks4 < 4; ++ks4) {
            int po = (ks4 * 4 + quad) * 128 + l16 * 8;
            f16x8 a2_0 = *(const f16x8*)&tbuf[wave][0][po];
            f16x8 a2_1 = *(const f16x8*)&tbuf[wave][1][po];
            #pragma unroll
            for (int nt = 0; nt < 8; ++nt) {
                f16x8 bfr = *(const f16x8*)&wbuf[(nt * 4 + ks4) * 512 + lane * 8];
                acc2[0][nt] = __builtin_amdgcn_mfma_f32_16x16x32_f16(a2_0, bfr, acc2[0][nt], 0, 0, 0);
                acc2[1][nt] = __builtin_amdgcn_mfma_f32_16x16x32_f16(a2_1, bfr, acc2[1][nt], 0, 0, 0);
            }
        }
        __syncthreads();
    }

    #pragma unroll
    for (int nt = 0; nt < 8; ++nt) {
        int cg = nt * 16 + l16;
        float sc = scale2[cg];
        float sh = shift2[cg];
        #pragma unroll
        for (int tt = 0; tt < 2; ++tt)
            #pragma unroll
            for (int r = 0; r < 4; ++r)
                acc2[tt][nt][r] = acc2[tt][nt][r] * sc + sh;
    }
    if (!last) {
        #pragma unroll
        for (int tt = 0; tt < 2; ++tt) {
            const int R0 = (mt0 + tt) * 16;
            #pragma unroll
            for (int nt = 0; nt < 8; ++nt) {
                int cg = nt * 16 + l16;
                #pragma unroll
                for (int r = 0; r < 4; ++r) {
                    int rg = R0 + quad * 4 + r;
                    if (rg < N_NODES) {
                        float val = fmaxf(acc2[tt][nt][r], 0.0f);
                        h16out[(size_t)rg * DIM + cg] =
                            __builtin_bit_cast(unsigned short, (_Float16)val);
                        unsigned int pk = (unsigned int)
                            __builtin_amdgcn_cvt_pk_fp8_f32(val, 0.0f, 0, false);
                        h8out[(size_t)rg * DIM + cg] = (unsigned char)(pk & 0xFF);
                    }
                }
            }
        }
    } else {
        #pragma unroll
        for (int tt = 0; tt < 2; ++tt) {
            const int R0 = (mt0 + tt) * 16;
            #pragma unroll
            for (int r = 0; r < 4; ++r) {
                float mx = acc2[tt][0][r];
                #pragma unroll
                for (int nt = 1; nt < 8; ++nt) mx = fmaxf(mx, acc2[tt][nt][r]);
                #pragma unroll
                for (int off = 1; off < 16; off <<= 1) mx = fmaxf(mx, __shfl_xor(mx, off, 64));
                float sum = 0.0f;
                #pragma unroll
                for (int nt = 0; nt < 8; ++nt) sum += expf(acc2[tt][nt][r] - mx);
                #pragma unroll
                for (int off = 1; off < 16; off <<= 1) sum += __shfl_xor(sum, off, 64);
                float ls = mx + logf(sum);
                int rg = R0 + quad * 4 + r;
                if (rg < N_NODES) {
                    #pragma unroll
                    for (int nt = 0; nt < 8; ++nt)
                        lsout[(size_t)rg * DIM + nt * 16 + l16] = acc2[tt][nt][r] - ls;
                }
            }
        }
    }
}

extern "C" void kernel_launch(void* const* d_in, const int* in_sizes, int n_in,
                              void* d_out, int out_size, void* d_ws, size_t ws_size,
                              hipStream_t stream) {
    const float* x   = (const float*)d_in[0];
    const int*   ei  = (const int*)d_in[1];
    const float* W1  = (const float*)d_in[2];
    const float* b1  = (const float*)d_in[3];
    const float* g1  = (const float*)d_in[4];
    const float* be1 = (const float*)d_in[5];
    const float* m1  = (const float*)d_in[6];
    const float* v1  = (const float*)d_in[7];
    const float* W2  = (const float*)d_in[8];
    const float* b2  = (const float*)d_in[9];
    const float* eps = (const float*)d_in[10];
    const float* go  = (const float*)d_in[11];
    const float* bo  = (const float*)d_in[12];
    const float* mo  = (const float*)d_in[13];
    const float* vo  = (const float*)d_in[14];

    char* ws = (char*)d_ws;
    unsigned short* h16 = (unsigned short*)ws;  ws += (size_t)N_NODES * DIM * 2;
    unsigned char* h8 = (unsigned char*)ws;     ws += (size_t)N_NODES * DIM;
    unsigned short* zf = (unsigned short*)ws;   ws += (size_t)MTPAD * 2048 * 2;
    _Float16* w1f = (_Float16*)ws;              ws += (size_t)L_LAYERS * 32768 * 2;
    _Float16* w2f = (_Float16*)ws;              ws += (size_t)L_LAYERS * 32768 * 2;
    float* scale1 = (float*)ws; ws += (size_t)L_LAYERS * 256 * 4;
    float* shift1 = (float*)ws; ws += (size_t)L_LAYERS * 256 * 4;
    float* scale2 = (float*)ws; ws += (size_t)L_LAYERS * 128 * 4;
    float* shift2 = (float*)ws; ws += (size_t)L_LAYERS * 128 * 4;
    unsigned int* brec = (unsigned int*)ws; ws += (size_t)NBUCK * BCAP * 4;
    int* gcur = (int*)ws; ws += 128 * 4;
    int* rowp = (int*)ws; ws += (size_t)(N_NODES + 1) * 4;
    unsigned short* col = (unsigned short*)ws; ws += (size_t)E_EDGES * 2;

    setup_kernel<<<CVT_BLOCKS + TRANS_BLOCKS + PREP_BLOCKS + 1, 256, 0, stream>>>(
        (const float4*)x, (f16x4*)h16, (unsigned int*)h8, W1, W2, w1f, w2f,
        b1, g1, be1, m1, v1, b2, go, bo, mo, vo,
        scale1, shift1, scale2, shift2, gcur);
    bin_kernel<<<(E_EDGES + 4095) / 4096, 256, 0, stream>>>(ei, gcur, brec);
    bsort_kernel<<<NBUCK, 512, 0, stream>>>(brec, gcur, rowp, col);

    for (int i = 0; i < L_LAYERS; ++i) {
        aggregate_kernel<<<N_NODES / 4, 256, 0, stream>>>((const unsigned int*)h16,
                                                          (const unsigned int*)h8,
                                                          rowp, col, eps + i, zf);
        int last = (i == L_LAYERS - 1) ? 1 : 0;
        mlp_kernel<<<MTPAD / 8, 256, 0, stream>>>((const _Float16*)zf,
            w1f + (size_t)i * 32768, w2f + (size_t)i * 32768,
            scale1 + i * 256, shift1 + i * 256,
            scale2 + i * 128, shift2 + i * 128,
            last, h16, h8, (float*)d_out);
    }
}